// Round 7
// baseline (262.244 us; speedup 1.0000x reference)
//
#include <hip/hip_runtime.h>
#include <math.h>

// ---------------------------------------------------------------------------
// 2-layer GCN, commuted form:  layer(X) = act((M·X)@W + b),  M = D^-1/2(A+I)D^-1/2
// Gather: one edge per wave-iteration (64 lanes x 2 bf16), rows sequential per
// wave (load-balanced); fp32 accumulate. GEMM reads W direct from global
// (L1/L2-resident) -> LDS = sM only (18.4 KB, 8 blocks/CU), single barrier.
// CSR built per call: (convert|histogram) -> chained scan -> scatter.
// ---------------------------------------------------------------------------

#define SCAN_CHUNK 8192
#define RPB 32                      // node rows per fused block

__device__ __forceinline__ unsigned short f2bf(float f) {
    unsigned u = __float_as_uint(f);
    unsigned r = (u + 0x7fff + ((u >> 16) & 1)) >> 16;   // RTNE
    return (unsigned short)r;
}
__device__ __forceinline__ unsigned pk2(float a, float b) {
    return (unsigned)f2bf(a) | ((unsigned)f2bf(b) << 16);
}
__device__ __forceinline__ float bf_lo(unsigned u) { return __uint_as_float(u << 16); }
__device__ __forceinline__ float bf_hi(unsigned u) { return __uint_as_float(u & 0xffff0000u); }

// blocks [0,CB): convert x -> bf16 (8 elems/thread); blocks [CB,...): degree histogram
__global__ __launch_bounds__(256) void k_prep(const float* __restrict__ x,
                                              unsigned short* __restrict__ xh, int nElem,
                                              const int* __restrict__ dst, int* cnt,
                                              int* __restrict__ epos, int e, int CB) {
    if ((int)blockIdx.x < CB) {
        int i8 = (blockIdx.x * 256 + threadIdx.x) * 8;
        if (i8 < nElem) {
            float4 v0 = *(const float4*)&x[i8];
            float4 v1 = *(const float4*)&x[i8 + 4];
            uint4 o;
            o.x = pk2(v0.x, v0.y); o.y = pk2(v0.z, v0.w);
            o.z = pk2(v1.x, v1.y); o.w = pk2(v1.z, v1.w);
            *(uint4*)&xh[i8] = o;
        }
    } else {
        int i = (blockIdx.x - CB) * 256 + threadIdx.x;
        if (i < e) epos[i] = atomicAdd(&cnt[dst[i]], 1);
    }
}

// Single-kernel chained exclusive scan (nb blocks, 8192 elems each); emits dinv.
__global__ __launch_bounds__(256) void k_scan1(const int* __restrict__ cnt,
                                               int* __restrict__ rowptr, float* __restrict__ dinv,
                                               int* __restrict__ flg, int* __restrict__ incl,
                                               int n, int nb) {
    __shared__ int part[256];
    __shared__ int sPrev;
    const int t   = threadIdx.x;
    const int blk = blockIdx.x;
    const int base = blk * SCAN_CHUNK + t * 32;
    int v[32];
    int s = 0;
#pragma unroll
    for (int q = 0; q < 32; ++q) {
        int i = base + q;
        v[q] = (i < n) ? cnt[i] : 0;
        s += v[q];
    }
    part[t] = s;
    __syncthreads();
    for (int off = 1; off < 256; off <<= 1) {
        int u = (t >= off) ? part[t - off] : 0;
        __syncthreads();
        part[t] += u;
        __syncthreads();
    }
    if (t == 0) {
        int prev = 0;
        if (blk > 0) {
            while (__hip_atomic_load(&flg[blk - 1], __ATOMIC_ACQUIRE, __HIP_MEMORY_SCOPE_AGENT) == 0) {}
            prev = __hip_atomic_load(&incl[blk - 1], __ATOMIC_RELAXED, __HIP_MEMORY_SCOPE_AGENT);
        }
        const int total = part[255];
        __hip_atomic_store(&incl[blk], prev + total, __ATOMIC_RELAXED, __HIP_MEMORY_SCOPE_AGENT);
        __hip_atomic_store(&flg[blk], 1, __ATOMIC_RELEASE, __HIP_MEMORY_SCOPE_AGENT);
        if (blk == nb - 1) rowptr[n] = prev + total;
        sPrev = prev;
    }
    __syncthreads();
    int run = sPrev + part[t] - s;
#pragma unroll
    for (int q = 0; q < 32; ++q) {
        int i = base + q;
        if (i < n) {
            rowptr[i] = run;
            dinv[i]   = rsqrtf((float)(v[q] + 1));   // +1 self-loop
            run += v[q];
        }
    }
}

// Packed edge records sorted by dst: (src, dinv[src]*dinv[dst])
__global__ __launch_bounds__(256) void k_fill(const int* __restrict__ src, const int* __restrict__ dst,
                                              const int* __restrict__ rowptr, const int* __restrict__ epos,
                                              const float* __restrict__ dinv,
                                              int2* __restrict__ erec, int e) {
    int i = blockIdx.x * blockDim.x + threadIdx.x;
    if (i < e) {
        int d = dst[i];
        int s = src[i];
        erec[rowptr[d] + epos[i]] = make_int2(s, __float_as_int(dinv[s] * dinv[d]));
    }
}

// ---------------------------------------------------------------------------
// Fused layer: Out[r] = act((M·Xh)[r] @ W + bias), RPB=32 rows / 256-thr block.
// Gather: each wave owns 8 rows sequentially; per edge, 64 lanes load one
// dword (2 bf16) each; 4 edges batched with next-batch record prefetch.
// GEMM: fp32, W read directly from global (L1/L2-cached); single barrier.
// OUTBF: epilogue stores bf16 (layer 1 -> a1) else fp32 (layer 2 -> d_out).
// ---------------------------------------------------------------------------
template <int COLS, int TR, bool RELU, bool OUTBF>
__global__ __launch_bounds__(256, 6) void fused_layer(const unsigned short* __restrict__ Xh,
                                                      const float* __restrict__ W,
                                                      const float* __restrict__ bias,
                                                      const int* __restrict__ rowptr,
                                                      const int2* __restrict__ erec,
                                                      void* __restrict__ OutP, int n) {
    constexpr int PAD = RPB + 4;                 // 36 floats (16B multiple)
    __shared__ __align__(16) float sM[128][PAD];

    const int t    = threadIdx.x;
    const int lane = t & 63;
    const int wv   = t >> 6;                     // wave 0..3
    const int row0 = blockIdx.x * RPB;
    const unsigned* __restrict__ Xu = (const unsigned*)Xh;   // row = 64 dwords

    // ---- gather: wave wv handles rows row0+wv*8 .. +8 sequentially ----
    {
        // preload row ptr bounds (9 scalar loads) and self rows (8 loads) upfront
        int bnd[9];
#pragma unroll
        for (int q = 0; q < 9; ++q) {
            int d = row0 + wv * 8 + q;
            bnd[q] = rowptr[min(d, n)];
        }
        unsigned su[8];
#pragma unroll
        for (int q = 0; q < 8; ++q) {
            int d = row0 + wv * 8 + q;
            su[q] = (d < n) ? Xu[(size_t)d * 64 + lane] : 0u;
        }
        const int2 Z = make_int2(0, 0);
#pragma unroll 1
        for (int rr = 0; rr < 8; ++rr) {
            const int d = row0 + wv * 8 + rr;
            const int r = wv * 8 + rr;
            float g0 = 0.f, g1 = 0.f;
            if (d < n) {
                const int beg = bnd[rr], end = bnd[rr + 1];
                const float wd2 = 1.0f / (float)(end - beg + 1);   // dinv[d]^2 exactly
                g0 = wd2 * bf_lo(su[rr]);
                g1 = wd2 * bf_hi(su[rr]);
                int j = beg;
                int2 p0 = (j     < end) ? erec[j]     : Z;
                int2 p1 = (j + 1 < end) ? erec[j + 1] : Z;
                int2 p2 = (j + 2 < end) ? erec[j + 2] : Z;
                int2 p3 = (j + 3 < end) ? erec[j + 3] : Z;
                while (j < end) {
                    const int2 c0 = p0, c1 = p1, c2 = p2, c3 = p3;
                    const int jn = j + 4;
                    p0 = (jn     < end) ? erec[jn]     : Z;   // prefetch next quad
                    p1 = (jn + 1 < end) ? erec[jn + 1] : Z;
                    p2 = (jn + 2 < end) ? erec[jn + 2] : Z;
                    p3 = (jn + 3 < end) ? erec[jn + 3] : Z;
                    unsigned u0 = Xu[(size_t)c0.x * 64 + lane];  // 4 independent 256B
                    unsigned u1 = Xu[(size_t)c1.x * 64 + lane];  // wave-reads in flight
                    unsigned u2 = Xu[(size_t)c2.x * 64 + lane];
                    unsigned u3 = Xu[(size_t)c3.x * 64 + lane];
                    const float w0 = __int_as_float(c0.y);       // 0 for tail slots
                    const float w1 = __int_as_float(c1.y);
                    const float w2 = __int_as_float(c2.y);
                    const float w3 = __int_as_float(c3.y);
                    g0 += w0 * bf_lo(u0); g1 += w0 * bf_hi(u0);
                    g0 += w1 * bf_lo(u1); g1 += w1 * bf_hi(u1);
                    g0 += w2 * bf_lo(u2); g1 += w2 * bf_hi(u2);
                    g0 += w3 * bf_lo(u3); g1 += w3 * bf_hi(u3);
                    j = jn;
                }
            }
            sM[2 * lane][r]     = g0;
            sM[2 * lane + 1][r] = g1;
        }
    }
    __syncthreads();

    // ---- GEMM: acc[TR][4] per thread; W straight from global ----
    const int tcx = t % (COLS / 4);
    const int tcy = t / (COLS / 4);
    float acc[TR][4] = {};
    const float4* __restrict__ Wp = (const float4*)W;

#pragma unroll 8
    for (int k = 0; k < 128; ++k) {
        float4 b = Wp[(size_t)k * (COLS / 4) + tcx];   // coalesced, L1/L2-resident
        float av[TR];
        if constexpr (TR == 4) {
            float4 a = *(const float4*)&sM[k][tcy * 4];  // wave-broadcast read
            av[0] = a.x; av[1] = a.y; av[2] = a.z; av[3] = a.w;
        } else {
            float2 a = *(const float2*)&sM[k][tcy * 2];
            av[0] = a.x; av[1] = a.y;
        }
        float bv[4] = {b.x, b.y, b.z, b.w};
#pragma unroll
        for (int ii = 0; ii < TR; ++ii)
#pragma unroll
            for (int jj = 0; jj < 4; ++jj) acc[ii][jj] += av[ii] * bv[jj];
    }

    // ---- epilogue ----
    float4 bv4 = *(const float4*)&bias[tcx * 4];
    float bb[4] = {bv4.x, bv4.y, bv4.z, bv4.w};
#pragma unroll
    for (int ii = 0; ii < TR; ++ii) {
        int rr = row0 + tcy * TR + ii;
        if (rr < n) {
            float o[4];
#pragma unroll
            for (int jj = 0; jj < 4; ++jj) {
                o[jj] = acc[ii][jj] + bb[jj];
                if (RELU) o[jj] = fmaxf(o[jj], 0.f);
            }
            if constexpr (OUTBF) {
                ushort4 ov;
                ov.x = f2bf(o[0]); ov.y = f2bf(o[1]); ov.z = f2bf(o[2]); ov.w = f2bf(o[3]);
                *(ushort4*)&((unsigned short*)OutP)[(size_t)rr * COLS + tcx * 4] = ov;
            } else {
                *(float4*)&((float*)OutP)[(size_t)rr * COLS + tcx * 4] =
                    make_float4(o[0], o[1], o[2], o[3]);
            }
        }
    }
}

// ---------------------------------------------------------------------------

extern "C" void kernel_launch(void* const* d_in, const int* in_sizes, int n_in,
                              void* d_out, int out_size, void* d_ws, size_t ws_size,
                              hipStream_t stream) {
    const float* x  = (const float*)d_in[0];
    const int*   ei = (const int*)d_in[1];
    const float* W1 = (const float*)d_in[2];
    const float* b1 = (const float*)d_in[3];
    const float* W2 = (const float*)d_in[4];
    const float* b2 = (const float*)d_in[5];
    float* out = (float*)d_out;

    const int N = in_sizes[0] / 128;
    const int E = in_sizes[1] / 2;
    const int* src = ei;
    const int* dst = ei + E;
    const int NB = (N + SCAN_CHUNK - 1) / SCAN_CHUNK;   // 7 for N=50000

    // workspace carve (256B aligned)
    size_t off = 0;
    char* base = (char*)d_ws;
    auto carve = [&](size_t bytes) -> void* {
        void* p = base + off;
        off += (bytes + 255) & ~(size_t)255;
        return p;
    };
    int*   cnt    = (int*)carve((size_t)N * 4);         // | zeroed as one span
    int*   flg    = (int*)carve((size_t)NB * 4);        // |
    int*   incl   = (int*)carve((size_t)NB * 4);        // |
    size_t zspan  = off;
    int*   rowptr = (int*)carve((size_t)(N + 1) * 4);
    float* dinv   = (float*)carve((size_t)N * 4);
    int2*  erec   = (int2*)carve((size_t)E * 8);
    unsigned short* xh = (unsigned short*)carve((size_t)N * 128 * 2);
    unsigned short* a1 = (unsigned short*)carve((size_t)N * 128 * 2);
    int*   epos   = (int*)a1;   // alias: epos dead before a1 is written (L1 epilogue)

    if (off > ws_size) return;  // diagnostic guard

    // 1) bf16 convert + degree histogram (one launch), chained scan, scatter
    const int nElem = N * 128;
    const int CB = (nElem / 8 + 255) / 256;
    const int EB = (E + 255) / 256;
    hipMemsetAsync(cnt, 0, zspan, stream);
    k_prep <<<CB + EB, 256, 0, stream>>>(x, xh, nElem, dst, cnt, epos, E, CB);
    k_scan1<<<NB, 256, 0, stream>>>(cnt, rowptr, dinv, flg, incl, N, NB);
    k_fill <<<EB, 256, 0, stream>>>(src, dst, rowptr, epos, dinv, erec, E);

    const int nblk = (N + RPB - 1) / RPB;
    // 2) layer 1: a1 = bf16(relu((M xh) @ W1 + b1))
    fused_layer<128, 4, true, true><<<nblk, 256, 0, stream>>>(
        xh, W1, b1, rowptr, erec, a1, N);
    // 3) layer 2: out = (M a1) @ W2 + b2   (fp32 out)
    fused_layer<64, 2, false, false><<<nblk, 256, 0, stream>>>(
        a1, W2, b2, rowptr, erec, out, N);
}

// Round 8
// 236.773 us; speedup vs baseline: 1.1076x; 1.1076x over previous
//
#include <hip/hip_runtime.h>
#include <math.h>

// ---------------------------------------------------------------------------
// 2-layer GCN, commuted form:  layer(X) = act((M·X)@W + b),  M = D^-1/2(A+I)D^-1/2
// Gather: R6 structure — 8 lanes/row, 16 bf16 feats/lane (2x uint4), 4-edge
// pipeline with quad record prefetch (32 edges in flight per wave).
// GEMM: 1 col x 16 rows per thread; W from global (1 dword/thread/k, coalesced,
// 16-deep chunks); sM reads are wave-broadcast. LDS = sM only (18.4 KB).
// CSR built per call: (convert|histogram) -> chained scan -> scatter.
// ---------------------------------------------------------------------------

#define SCAN_CHUNK 8192
#define RPB 32                      // node rows per fused block

__device__ __forceinline__ unsigned short f2bf(float f) {
    unsigned u = __float_as_uint(f);
    unsigned r = (u + 0x7fff + ((u >> 16) & 1)) >> 16;   // RTNE
    return (unsigned short)r;
}
__device__ __forceinline__ unsigned pk2(float a, float b) {
    return (unsigned)f2bf(a) | ((unsigned)f2bf(b) << 16);
}
__device__ __forceinline__ float bf_lo(unsigned u) { return __uint_as_float(u << 16); }
__device__ __forceinline__ float bf_hi(unsigned u) { return __uint_as_float(u & 0xffff0000u); }

// blocks [0,CB): convert x -> bf16 (8 elems/thread); blocks [CB,...): degree histogram
__global__ __launch_bounds__(256) void k_prep(const float* __restrict__ x,
                                              unsigned short* __restrict__ xh, int nElem,
                                              const int* __restrict__ dst, int* cnt,
                                              int* __restrict__ epos, int e, int CB) {
    if ((int)blockIdx.x < CB) {
        int i8 = (blockIdx.x * 256 + threadIdx.x) * 8;
        if (i8 < nElem) {
            float4 v0 = *(const float4*)&x[i8];
            float4 v1 = *(const float4*)&x[i8 + 4];
            uint4 o;
            o.x = pk2(v0.x, v0.y); o.y = pk2(v0.z, v0.w);
            o.z = pk2(v1.x, v1.y); o.w = pk2(v1.z, v1.w);
            *(uint4*)&xh[i8] = o;
        }
    } else {
        int i = (blockIdx.x - CB) * 256 + threadIdx.x;
        if (i < e) epos[i] = atomicAdd(&cnt[dst[i]], 1);
    }
}

// Single-kernel chained exclusive scan (nb blocks, 8192 elems each); emits dinv.
__global__ __launch_bounds__(256) void k_scan1(const int* __restrict__ cnt,
                                               int* __restrict__ rowptr, float* __restrict__ dinv,
                                               int* __restrict__ flg, int* __restrict__ incl,
                                               int n, int nb) {
    __shared__ int part[256];
    __shared__ int sPrev;
    const int t   = threadIdx.x;
    const int blk = blockIdx.x;
    const int base = blk * SCAN_CHUNK + t * 32;
    int v[32];
    int s = 0;
#pragma unroll
    for (int q = 0; q < 32; ++q) {
        int i = base + q;
        v[q] = (i < n) ? cnt[i] : 0;
        s += v[q];
    }
    part[t] = s;
    __syncthreads();
    for (int off = 1; off < 256; off <<= 1) {
        int u = (t >= off) ? part[t - off] : 0;
        __syncthreads();
        part[t] += u;
        __syncthreads();
    }
    if (t == 0) {
        int prev = 0;
        if (blk > 0) {
            while (__hip_atomic_load(&flg[blk - 1], __ATOMIC_ACQUIRE, __HIP_MEMORY_SCOPE_AGENT) == 0) {}
            prev = __hip_atomic_load(&incl[blk - 1], __ATOMIC_RELAXED, __HIP_MEMORY_SCOPE_AGENT);
        }
        const int total = part[255];
        __hip_atomic_store(&incl[blk], prev + total, __ATOMIC_RELAXED, __HIP_MEMORY_SCOPE_AGENT);
        __hip_atomic_store(&flg[blk], 1, __ATOMIC_RELEASE, __HIP_MEMORY_SCOPE_AGENT);
        if (blk == nb - 1) rowptr[n] = prev + total;
        sPrev = prev;
    }
    __syncthreads();
    int run = sPrev + part[t] - s;
#pragma unroll
    for (int q = 0; q < 32; ++q) {
        int i = base + q;
        if (i < n) {
            rowptr[i] = run;
            dinv[i]   = rsqrtf((float)(v[q] + 1));   // +1 self-loop
            run += v[q];
        }
    }
}

// Packed edge records sorted by dst: (src, dinv[src]*dinv[dst])
__global__ __launch_bounds__(256) void k_fill(const int* __restrict__ src, const int* __restrict__ dst,
                                              const int* __restrict__ rowptr, const int* __restrict__ epos,
                                              const float* __restrict__ dinv,
                                              int2* __restrict__ erec, int e) {
    int i = blockIdx.x * blockDim.x + threadIdx.x;
    if (i < e) {
        int d = dst[i];
        int s = src[i];
        erec[rowptr[d] + epos[i]] = make_int2(s, __float_as_int(dinv[s] * dinv[d]));
    }
}

// ---------------------------------------------------------------------------
// Fused layer: Out[r] = act((M·Xh)[r] @ W + bias), RPB=32 rows / 256-thr block.
// acc16: 16 bf16-pair fmas into ga[16]
// ---------------------------------------------------------------------------
__device__ __forceinline__ void acc16(float* ga, float c, uint4 u0, uint4 u1) {
    ga[0]  += c * bf_lo(u0.x); ga[1]  += c * bf_hi(u0.x);
    ga[2]  += c * bf_lo(u0.y); ga[3]  += c * bf_hi(u0.y);
    ga[4]  += c * bf_lo(u0.z); ga[5]  += c * bf_hi(u0.z);
    ga[6]  += c * bf_lo(u0.w); ga[7]  += c * bf_hi(u0.w);
    ga[8]  += c * bf_lo(u1.x); ga[9]  += c * bf_hi(u1.x);
    ga[10] += c * bf_lo(u1.y); ga[11] += c * bf_hi(u1.y);
    ga[12] += c * bf_lo(u1.z); ga[13] += c * bf_hi(u1.z);
    ga[14] += c * bf_lo(u1.w); ga[15] += c * bf_hi(u1.w);
}

template <int COLS, bool RELU, bool OUTBF>
__global__ __launch_bounds__(256, 6) void fused_layer(const unsigned short* __restrict__ Xh,
                                                      const float* __restrict__ W,
                                                      const float* __restrict__ bias,
                                                      const int* __restrict__ rowptr,
                                                      const int2* __restrict__ erec,
                                                      void* __restrict__ OutP, int n) {
    constexpr int PAD = RPB + 4;                 // 36 floats
    __shared__ __align__(16) float sM[128][PAD];

    const int t    = threadIdx.x;
    const int row0 = blockIdx.x * RPB;

    // ---- gather (R6 structure): 8 lanes/row, 4-edge pipeline ----
    {
        const int r     = t >> 3;                // row-in-block 0..31
        const int lane2 = (t & 7) * 2;           // uint4 index within 256B row
        const int seg   = (t & 7) * 16;          // feature base
        const int d     = row0 + r;
        if (d < n) {
            const int beg = rowptr[d], end = rowptr[d + 1];
            const float wd2 = 1.0f / (float)(end - beg + 1);   // dinv[d]^2 exactly
            float ga[16] = {};
            {
                const uint4* P = (const uint4*)(Xh + ((size_t)d << 7)) + lane2;
                acc16(ga, wd2, P[0], P[1]);
            }
            int j = beg;
            const int2 Z = make_int2(0, 0);
            int2 p0 = (j     < end) ? erec[j]     : Z;
            int2 p1 = (j + 1 < end) ? erec[j + 1] : Z;
            int2 p2 = (j + 2 < end) ? erec[j + 2] : Z;
            int2 p3 = (j + 3 < end) ? erec[j + 3] : Z;
            while (j < end) {
                const int2 c0 = p0, c1 = p1, c2 = p2, c3 = p3;
                const int jn = j + 4;
                p0 = (jn     < end) ? erec[jn]     : Z;   // prefetch next quad
                p1 = (jn + 1 < end) ? erec[jn + 1] : Z;
                p2 = (jn + 2 < end) ? erec[jn + 2] : Z;
                p3 = (jn + 3 < end) ? erec[jn + 3] : Z;
                const uint4* P0 = (const uint4*)(Xh + ((size_t)c0.x << 7)) + lane2;
                const uint4* P1 = (const uint4*)(Xh + ((size_t)c1.x << 7)) + lane2;
                const uint4* P2 = (const uint4*)(Xh + ((size_t)c2.x << 7)) + lane2;
                const uint4* P3 = (const uint4*)(Xh + ((size_t)c3.x << 7)) + lane2;
                uint4 a0 = P0[0], a1 = P0[1];                // 8 independent 16B loads
                uint4 b0 = P1[0], b1 = P1[1];
                uint4 d0 = P2[0], d1 = P2[1];
                uint4 e0 = P3[0], e1 = P3[1];
                acc16(ga, __int_as_float(c0.y), a0, a1);     // coef 0 for tail slots
                acc16(ga, __int_as_float(c1.y), b0, b1);
                acc16(ga, __int_as_float(c2.y), d0, d1);
                acc16(ga, __int_as_float(c3.y), e0, e1);
                j = jn;
            }
#pragma unroll
            for (int q = 0; q < 16; ++q) sM[seg + q][r] = ga[q];
        } else {
#pragma unroll
            for (int q = 0; q < 16; ++q) sM[(t & 7) * 16 + q][t >> 3] = 0.f;
        }
    }
    __syncthreads();

    // ---- GEMM: 1 col x RPT rows per thread; W from global, 16-deep chunks ----
    constexpr int RPT = RPB * COLS / 256;        // 16 (COLS=128) or 8 (COLS=64)
    const int col = t % COLS;
    const int rg  = t / COLS;
    const int rb  = rg * RPT;                    // row base within block
    float acc[RPT] = {};
    const float* __restrict__ Wc = W + col;

    for (int kc = 0; kc < 128; kc += 16) {
        float wv[16];
#pragma unroll
        for (int q = 0; q < 16; ++q)
            wv[q] = Wc[(size_t)(kc + q) * COLS];  // coalesced 256B/wave, L1/L2
#pragma unroll
        for (int q = 0; q < 16; ++q) {
            const float* a = &sM[kc + q][rb];      // wave-broadcast LDS reads
#pragma unroll
            for (int i = 0; i < RPT; i += 4) {
                float4 a4 = *(const float4*)&a[i];
                acc[i + 0] += a4.x * wv[q];
                acc[i + 1] += a4.y * wv[q];
                acc[i + 2] += a4.z * wv[q];
                acc[i + 3] += a4.w * wv[q];
            }
        }
    }

    // ---- epilogue: bias (+ReLU), coalesced column stores ----
    const float bb = bias[col];
#pragma unroll
    for (int i = 0; i < RPT; ++i) {
        int rr = row0 + rb + i;
        if (rr < n) {
            float o = acc[i] + bb;
            if (RELU) o = fmaxf(o, 0.f);
            if constexpr (OUTBF)
                ((unsigned short*)OutP)[(size_t)rr * COLS + col] = f2bf(o);
            else
                ((float*)OutP)[(size_t)rr * COLS + col] = o;
        }
    }
}

// ---------------------------------------------------------------------------

extern "C" void kernel_launch(void* const* d_in, const int* in_sizes, int n_in,
                              void* d_out, int out_size, void* d_ws, size_t ws_size,
                              hipStream_t stream) {
    const float* x  = (const float*)d_in[0];
    const int*   ei = (const int*)d_in[1];
    const float* W1 = (const float*)d_in[2];
    const float* b1 = (const float*)d_in[3];
    const float* W2 = (const float*)d_in[4];
    const float* b2 = (const float*)d_in[5];
    float* out = (float*)d_out;

    const int N = in_sizes[0] / 128;
    const int E = in_sizes[1] / 2;
    const int* src = ei;
    const int* dst = ei + E;
    const int NB = (N + SCAN_CHUNK - 1) / SCAN_CHUNK;   // 7 for N=50000

    // workspace carve (256B aligned)
    size_t off = 0;
    char* base = (char*)d_ws;
    auto carve = [&](size_t bytes) -> void* {
        void* p = base + off;
        off += (bytes + 255) & ~(size_t)255;
        return p;
    };
    int*   cnt    = (int*)carve((size_t)N * 4);         // | zeroed as one span
    int*   flg    = (int*)carve((size_t)NB * 4);        // |
    int*   incl   = (int*)carve((size_t)NB * 4);        // |
    size_t zspan  = off;
    int*   rowptr = (int*)carve((size_t)(N + 1) * 4);
    float* dinv   = (float*)carve((size_t)N * 4);
    int2*  erec   = (int2*)carve((size_t)E * 8);
    unsigned short* xh = (unsigned short*)carve((size_t)N * 128 * 2);
    unsigned short* a1 = (unsigned short*)carve((size_t)N * 128 * 2);
    int*   epos   = (int*)a1;   // alias: epos dead before a1 is written (L1 epilogue)

    if (off > ws_size) return;  // diagnostic guard

    // 1) bf16 convert + degree histogram (one launch), chained scan, scatter
    const int nElem = N * 128;
    const int CB = (nElem / 8 + 255) / 256;
    const int EB = (E + 255) / 256;
    hipMemsetAsync(cnt, 0, zspan, stream);
    k_prep <<<CB + EB, 256, 0, stream>>>(x, xh, nElem, dst, cnt, epos, E, CB);
    k_scan1<<<NB, 256, 0, stream>>>(cnt, rowptr, dinv, flg, incl, N, NB);
    k_fill <<<EB, 256, 0, stream>>>(src, dst, rowptr, epos, dinv, erec, E);

    const int nblk = (N + RPB - 1) / RPB;
    // 2) layer 1: a1 = bf16(relu((M xh) @ W1 + b1))
    fused_layer<128, true, true><<<nblk, 256, 0, stream>>>(
        xh, W1, b1, rowptr, erec, a1, N);
    // 3) layer 2: out = (M a1) @ W2 + b2   (fp32 out)
    fused_layer<64, false, false><<<nblk, 256, 0, stream>>>(
        a1, W2, b2, rowptr, erec, out, N);
}

// Round 9
// 235.774 us; speedup vs baseline: 1.1123x; 1.0042x over previous
//
#include <hip/hip_runtime.h>
#include <hip/hip_fp16.h>
#include <math.h>

// ---------------------------------------------------------------------------
// 2-layer GCN:  out = M·relu((M·x)@W1 + b1)@W2 + b2,  M = D^-1/2(A+I)D^-1/2
// Layer 1 fused: gather(x,fp16) -> GEMM1(W1)+b1+relu -> GEMM2(W2) -> h2 (fp16,64)
// Layer 2: pure gather of 128B h2 rows + b2 -> out (fp32).
// Edge records are 4B (src | deg<<17); ws = rsqrt(deg+1) computed in-kernel.
// Gathers use a 2-stage software pipeline (8 edges in flight per row-group).
// ---------------------------------------------------------------------------

#define SCAN_CHUNK 8192

__device__ __forceinline__ unsigned ph2(float a, float b) {
    return (unsigned)__half_as_ushort(__float2half_rn(a)) |
           ((unsigned)__half_as_ushort(__float2half_rn(b)) << 16);
}
__device__ __forceinline__ float h_lo(unsigned u) {
    return __half2float(__ushort_as_half((unsigned short)(u & 0xffffu)));
}
__device__ __forceinline__ float h_hi(unsigned u) {
    return __half2float(__ushort_as_half((unsigned short)(u >> 16)));
}

// 16 fp16 feats (2 uint4) FMA into ga[16]
__device__ __forceinline__ void acch16(float* ga, float c, uint4 u0, uint4 u1) {
    ga[0]  += c * h_lo(u0.x); ga[1]  += c * h_hi(u0.x);
    ga[2]  += c * h_lo(u0.y); ga[3]  += c * h_hi(u0.y);
    ga[4]  += c * h_lo(u0.z); ga[5]  += c * h_hi(u0.z);
    ga[6]  += c * h_lo(u0.w); ga[7]  += c * h_hi(u0.w);
    ga[8]  += c * h_lo(u1.x); ga[9]  += c * h_hi(u1.x);
    ga[10] += c * h_lo(u1.y); ga[11] += c * h_hi(u1.y);
    ga[12] += c * h_lo(u1.z); ga[13] += c * h_hi(u1.z);
    ga[14] += c * h_lo(u1.w); ga[15] += c * h_hi(u1.w);
}
// 8 fp16 feats (1 uint4) FMA into ga[8]
__device__ __forceinline__ void acch8(float* ga, float c, uint4 u) {
    ga[0] += c * h_lo(u.x); ga[1] += c * h_hi(u.x);
    ga[2] += c * h_lo(u.y); ga[3] += c * h_hi(u.y);
    ga[4] += c * h_lo(u.z); ga[5] += c * h_hi(u.z);
    ga[6] += c * h_lo(u.w); ga[7] += c * h_hi(u.w);
}

// blocks [0,CB): convert x -> fp16 (8 elems/thread); blocks [CB,...): histogram
__global__ __launch_bounds__(256) void k_prep(const float* __restrict__ x,
                                              unsigned short* __restrict__ xh, int nElem,
                                              const int* __restrict__ dst, int* cnt,
                                              int* __restrict__ epos, int e, int CB) {
    if ((int)blockIdx.x < CB) {
        int i8 = (blockIdx.x * 256 + threadIdx.x) * 8;
        if (i8 < nElem) {
            float4 v0 = *(const float4*)&x[i8];
            float4 v1 = *(const float4*)&x[i8 + 4];
            uint4 o;
            o.x = ph2(v0.x, v0.y); o.y = ph2(v0.z, v0.w);
            o.z = ph2(v1.x, v1.y); o.w = ph2(v1.z, v1.w);
            *(uint4*)&xh[i8] = o;
        }
    } else {
        int i = (blockIdx.x - CB) * 256 + threadIdx.x;
        if (i < e) epos[i] = atomicAdd(&cnt[dst[i]], 1);
    }
}

// Single-kernel chained exclusive scan (nb blocks, 8192 elems each) -> rowptr.
__global__ __launch_bounds__(256) void k_scan1(const int* __restrict__ cnt,
                                               int* __restrict__ rowptr,
                                               int* __restrict__ flg, int* __restrict__ incl,
                                               int n, int nb) {
    __shared__ int part[256];
    __shared__ int sPrev;
    const int t   = threadIdx.x;
    const int blk = blockIdx.x;
    const int base = blk * SCAN_CHUNK + t * 32;
    int v[32];
    int s = 0;
#pragma unroll
    for (int q = 0; q < 32; ++q) {
        int i = base + q;
        v[q] = (i < n) ? cnt[i] : 0;
        s += v[q];
    }
    part[t] = s;
    __syncthreads();
    for (int off = 1; off < 256; off <<= 1) {
        int u = (t >= off) ? part[t - off] : 0;
        __syncthreads();
        part[t] += u;
        __syncthreads();
    }
    if (t == 0) {
        int prev = 0;
        if (blk > 0) {
            while (__hip_atomic_load(&flg[blk - 1], __ATOMIC_ACQUIRE, __HIP_MEMORY_SCOPE_AGENT) == 0) {}
            prev = __hip_atomic_load(&incl[blk - 1], __ATOMIC_RELAXED, __HIP_MEMORY_SCOPE_AGENT);
        }
        const int total = part[255];
        __hip_atomic_store(&incl[blk], prev + total, __ATOMIC_RELAXED, __HIP_MEMORY_SCOPE_AGENT);
        __hip_atomic_store(&flg[blk], 1, __ATOMIC_RELEASE, __HIP_MEMORY_SCOPE_AGENT);
        if (blk == nb - 1) rowptr[n] = prev + total;
        sPrev = prev;
    }
    __syncthreads();
    int run = sPrev + part[t] - s;
#pragma unroll
    for (int q = 0; q < 32; ++q) {
        int i = base + q;
        if (i < n) { rowptr[i] = run; run += v[q]; }
    }
}

// 4B edge records sorted by dst: src | (deg(src) << 17)
__global__ __launch_bounds__(256) void k_fill(const int* __restrict__ src, const int* __restrict__ dst,
                                              const int* __restrict__ rowptr, const int* __restrict__ epos,
                                              const int* __restrict__ cnt,
                                              unsigned* __restrict__ erec, int e) {
    int i = blockIdx.x * blockDim.x + threadIdx.x;
    if (i < e) {
        int d = dst[i];
        int s = src[i];
        erec[rowptr[d] + epos[i]] = (unsigned)s | ((unsigned)cnt[s] << 17);
    }
}

// ---------------------------------------------------------------------------
// Fused layer 1: h2 = relu((M·xh)@W1 + b1) @ W2   (fp16 out, 64 cols)
// 32 rows/block; gather 8 lanes/row, 2-stage pipeline (8 edges in flight).
// ---------------------------------------------------------------------------
__global__ __launch_bounds__(256, 4) void fused_l1(const unsigned short* __restrict__ Xh,
                                                   const float* __restrict__ W1,
                                                   const float* __restrict__ b1,
                                                   const float* __restrict__ W2,
                                                   const int* __restrict__ rowptr,
                                                   const unsigned* __restrict__ erec,
                                                   unsigned short* __restrict__ H2, int n) {
    __shared__ __align__(16) float sM[128][36];
    const int t    = threadIdx.x;
    const int row0 = blockIdx.x * 32;

    // ---- gather: u = wd*x_d + sum ws*x_s ; sM = wd*u ----
    {
        const int r     = t >> 3;
        const int lane2 = (t & 7) * 2;
        const int seg   = (t & 7) * 16;
        const int d     = row0 + r;
        float ga[16] = {};
        float wd = 0.f;
        if (d < n) {
            const int beg = rowptr[d], end = rowptr[d + 1];
            wd = rsqrtf((float)(end - beg + 1));
            const uint4* Pd = (const uint4*)(Xh + ((size_t)d << 7)) + lane2;
            uint4 s0 = Pd[0], s1 = Pd[1];
            acch16(ga, wd, s0, s1);
            auto ldr  = [&](int idx) -> unsigned { return (idx < end) ? erec[idx] : 0u; };
            auto rowp = [&](unsigned rec) -> const uint4* {
                return (const uint4*)(Xh + ((size_t)(rec & 0x1FFFFu) << 7)) + lane2;
            };
            auto cf = [&](unsigned rec, int idx) -> float {
                float c = rsqrtf((float)((rec >> 17) + 1));
                return (idx < end) ? c : 0.f;
            };
            int j = beg;
            unsigned rc0=ldr(j),rc1=ldr(j+1),rc2=ldr(j+2),rc3=ldr(j+3);
            unsigned rc4=ldr(j+4),rc5=ldr(j+5),rc6=ldr(j+6),rc7=ldr(j+7);
            const uint4* p;
            uint4 A0,A1,A2,A3,A4,A5,A6,A7;
            p=rowp(rc0); A0=p[0]; A1=p[1];
            p=rowp(rc1); A2=p[0]; A3=p[1];
            p=rowp(rc2); A4=p[0]; A5=p[1];
            p=rowp(rc3); A6=p[0]; A7=p[1];
            while (j < end) {
                uint4 B0,B1,B2,B3,B4,B5,B6,B7;
                p=rowp(rc4); B0=p[0]; B1=p[1];          // stage-B rows issue
                p=rowp(rc5); B2=p[0]; B3=p[1];
                p=rowp(rc6); B4=p[0]; B5=p[1];
                p=rowp(rc7); B6=p[0]; B7=p[1];
                unsigned n0=ldr(j+8),n1=ldr(j+9),n2=ldr(j+10),n3=ldr(j+11);
                unsigned n4=ldr(j+12),n5=ldr(j+13),n6=ldr(j+14),n7=ldr(j+15);
                acch16(ga, cf(rc0,j  ), A0,A1);          // consume stage A
                acch16(ga, cf(rc1,j+1), A2,A3);
                acch16(ga, cf(rc2,j+2), A4,A5);
                acch16(ga, cf(rc3,j+3), A6,A7);
                p=rowp(n0); A0=p[0]; A1=p[1];            // next stage-A rows issue
                p=rowp(n1); A2=p[0]; A3=p[1];
                p=rowp(n2); A4=p[0]; A5=p[1];
                p=rowp(n3); A6=p[0]; A7=p[1];
                acch16(ga, cf(rc4,j+4), B0,B1);          // consume stage B
                acch16(ga, cf(rc5,j+5), B2,B3);
                acch16(ga, cf(rc6,j+6), B4,B5);
                acch16(ga, cf(rc7,j+7), B6,B7);
                rc0=n0; rc1=n1; rc2=n2; rc3=n3;
                rc4=n4; rc5=n5; rc6=n6; rc7=n7;
                j += 8;
            }
        }
#pragma unroll
        for (int q = 0; q < 16; ++q) sM[seg + q][r] = wd * ga[q];
    }
    __syncthreads();

    // ---- GEMM1: 1 col x 16 rows per thread ----
    const int col = t & 127;
    const int rb  = (t >> 7) * 16;
    float acc[16] = {};
    {
        const float* Wc = W1 + col;
        for (int kc = 0; kc < 128; kc += 16) {
            float wv[16];
#pragma unroll
            for (int q = 0; q < 16; ++q) wv[q] = Wc[(size_t)(kc + q) << 7];
#pragma unroll
            for (int q = 0; q < 16; ++q) {
                const float* a = &sM[kc + q][rb];        // wave-broadcast
#pragma unroll
                for (int i = 0; i < 16; i += 4) {
                    float4 a4 = *(const float4*)&a[i];
                    acc[i+0] += a4.x * wv[q];
                    acc[i+1] += a4.y * wv[q];
                    acc[i+2] += a4.z * wv[q];
                    acc[i+3] += a4.w * wv[q];
                }
            }
        }
    }
    __syncthreads();
    // ---- restage relu(acc + b1) -> sM[col][row] (rotated: 4-way banks) ----
    {
        const float bb = b1[col];
#pragma unroll
        for (int i = 0; i < 16; ++i) {
            int idx = (i + col) & 15;
            sM[col][rb + idx] = fmaxf(acc[idx] + bb, 0.f);
        }
    }
    __syncthreads();

    // ---- GEMM2: 1 col x 8 rows per thread -> h2 fp16 ----
    {
        const int col2 = t & 63;
        const int rb2  = (t >> 6) * 8;
        float acc2[8] = {};
        const float* Wc2 = W2 + col2;
        for (int kc = 0; kc < 128; kc += 16) {
            float wv[16];
#pragma unroll
            for (int q = 0; q < 16; ++q) wv[q] = Wc2[(size_t)(kc + q) << 6];
#pragma unroll
            for (int q = 0; q < 16; ++q) {
                const float* a = &sM[kc + q][rb2];
                float4 a0 = *(const float4*)&a[0];
                float4 a1 = *(const float4*)&a[4];
                acc2[0] += a0.x * wv[q]; acc2[1] += a0.y * wv[q];
                acc2[2] += a0.z * wv[q]; acc2[3] += a0.w * wv[q];
                acc2[4] += a1.x * wv[q]; acc2[5] += a1.y * wv[q];
                acc2[6] += a1.z * wv[q]; acc2[7] += a1.w * wv[q];
            }
        }
#pragma unroll
        for (int i = 0; i < 8; ++i) {
            int rr = row0 + rb2 + i;
            if (rr < n)
                H2[(size_t)rr * 64 + col2] = __half_as_ushort(__float2half_rn(acc2[i]));
        }
    }
}

// ---------------------------------------------------------------------------
// Layer 2 aggregate: out = wd*(wd*h2_d + sum ws*h2_s) + b2  (fp32 out, 64 cols)
// 32 rows/block, 8 lanes/row (1 uint4 = 8 fp16 each), 2-stage pipeline.
// No LDS, no barrier.
// ---------------------------------------------------------------------------
__global__ __launch_bounds__(256, 6) void k_agg2(const unsigned short* __restrict__ H2,
                                                 const float* __restrict__ b2,
                                                 const int* __restrict__ rowptr,
                                                 const unsigned* __restrict__ erec,
                                                 float* __restrict__ out, int n) {
    const int t    = threadIdx.x;
    const int r    = t >> 3;
    const int lane = t & 7;
    const int d    = blockIdx.x * 32 + r;
    if (d >= n) return;
    const int beg = rowptr[d], end = rowptr[d + 1];
    const float wd = rsqrtf((float)(end - beg + 1));
    float ga[8] = {};
    {
        uint4 s = ((const uint4*)(H2 + ((size_t)d << 6)))[lane];
        acch8(ga, wd, s);
    }
    auto ldr  = [&](int idx) -> unsigned { return (idx < end) ? erec[idx] : 0u; };
    auto rowp = [&](unsigned rec) -> uint4 {
        return ((const uint4*)(H2 + ((size_t)(rec & 0x1FFFFu) << 6)))[lane];
    };
    auto cf = [&](unsigned rec, int idx) -> float {
        float c = rsqrtf((float)((rec >> 17) + 1));
        return (idx < end) ? c : 0.f;
    };
    int j = beg;
    unsigned rc0=ldr(j),rc1=ldr(j+1),rc2=ldr(j+2),rc3=ldr(j+3);
    unsigned rc4=ldr(j+4),rc5=ldr(j+5),rc6=ldr(j+6),rc7=ldr(j+7);
    uint4 A0=rowp(rc0), A1=rowp(rc1), A2=rowp(rc2), A3=rowp(rc3);
    while (j < end) {
        uint4 B0=rowp(rc4), B1=rowp(rc5), B2=rowp(rc6), B3=rowp(rc7);
        unsigned n0=ldr(j+8),n1=ldr(j+9),n2=ldr(j+10),n3=ldr(j+11);
        unsigned n4=ldr(j+12),n5=ldr(j+13),n6=ldr(j+14),n7=ldr(j+15);
        acch8(ga, cf(rc0,j  ), A0);
        acch8(ga, cf(rc1,j+1), A1);
        acch8(ga, cf(rc2,j+2), A2);
        acch8(ga, cf(rc3,j+3), A3);
        A0=rowp(n0); A1=rowp(n1); A2=rowp(n2); A3=rowp(n3);
        acch8(ga, cf(rc4,j+4), B0);
        acch8(ga, cf(rc5,j+5), B1);
        acch8(ga, cf(rc6,j+6), B2);
        acch8(ga, cf(rc7,j+7), B3);
        rc0=n0; rc1=n1; rc2=n2; rc3=n3;
        rc4=n4; rc5=n5; rc6=n6; rc7=n7;
        j += 8;
    }
    const int seg = lane * 8;
    const float4 bb0 = *(const float4*)&b2[seg];
    const float4 bb1 = *(const float4*)&b2[seg + 4];
    float4 o0, o1;
    o0.x = wd*ga[0] + bb0.x; o0.y = wd*ga[1] + bb0.y;
    o0.z = wd*ga[2] + bb0.z; o0.w = wd*ga[3] + bb0.w;
    o1.x = wd*ga[4] + bb1.x; o1.y = wd*ga[5] + bb1.y;
    o1.z = wd*ga[6] + bb1.z; o1.w = wd*ga[7] + bb1.w;
    float* orow = out + (size_t)d * 64 + seg;
    *(float4*)&orow[0] = o0;
    *(float4*)&orow[4] = o1;
}

// ---------------------------------------------------------------------------

extern "C" void kernel_launch(void* const* d_in, const int* in_sizes, int n_in,
                              void* d_out, int out_size, void* d_ws, size_t ws_size,
                              hipStream_t stream) {
    const float* x  = (const float*)d_in[0];
    const int*   ei = (const int*)d_in[1];
    const float* W1 = (const float*)d_in[2];
    const float* b1 = (const float*)d_in[3];
    const float* W2 = (const float*)d_in[4];
    const float* b2 = (const float*)d_in[5];
    float* out = (float*)d_out;

    const int N = in_sizes[0] / 128;
    const int E = in_sizes[1] / 2;
    const int* src = ei;
    const int* dst = ei + E;
    const int NB = (N + SCAN_CHUNK - 1) / SCAN_CHUNK;   // 7 for N=50000

    // workspace carve (256B aligned)
    size_t off = 0;
    char* base = (char*)d_ws;
    auto carve = [&](size_t bytes) -> void* {
        void* p = base + off;
        off += (bytes + 255) & ~(size_t)255;
        return p;
    };
    int*      cnt    = (int*)carve((size_t)N * 4);      // | zeroed as one span
    int*      flg    = (int*)carve((size_t)NB * 4);     // |
    int*      incl   = (int*)carve((size_t)NB * 4);     // |
    size_t    zspan  = off;
    int*      rowptr = (int*)carve((size_t)(N + 1) * 4);
    unsigned* erec   = (unsigned*)carve((size_t)E * 4);
    unsigned short* xh = (unsigned short*)carve((size_t)N * 128 * 2);
    unsigned short* h2 = (unsigned short*)carve((size_t)N * 64 * 2);
    int*      epos   = (int*)h2;   // alias: epos dead before h2 is written

    if (off > ws_size) return;  // diagnostic guard

    // 1) fp16 convert + histogram (one launch), chained scan, edge-record scatter
    const int nElem = N * 128;
    const int CB = (nElem / 8 + 255) / 256;
    const int EB = (E + 255) / 256;
    hipMemsetAsync(cnt, 0, zspan, stream);
    k_prep <<<CB + EB, 256, 0, stream>>>(x, xh, nElem, dst, cnt, epos, E, CB);
    k_scan1<<<NB, 256, 0, stream>>>(cnt, rowptr, flg, incl, N, NB);
    k_fill <<<EB, 256, 0, stream>>>(src, dst, rowptr, epos, cnt, erec, E);

    const int nblk = (N + 31) / 32;
    // 2) fused layer 1 (+ dense GEMM2): h2 = relu((M xh)@W1 + b1) @ W2
    fused_l1<<<nblk, 256, 0, stream>>>(xh, W1, b1, W2, rowptr, erec, h2, N);
    // 3) layer 2 aggregate: out = M h2 + b2
    k_agg2<<<nblk, 256, 0, stream>>>(h2, b2, rowptr, erec, out, N);
}